// Round 1
// baseline (323.531 us; speedup 1.0000x reference)
//
#include <hip/hip_runtime.h>
#include <math.h>

#define HIDDEN 2048
#define NEXP   64
#define BK     128          // k-chunk staged in LDS
#define NK4    (BK/4)       // 32 float4 steps per chunk
#define NCHUNK (HIDDEN/BK)  // 16
#define TPB    512          // 8 waves
#define TPW    8            // tokens per wave
#define TPBK   64           // tokens per block

__global__ __launch_bounds__(TPB, 4)
void router_kernel(const float* __restrict__ x,
                   const float* __restrict__ Wg,
                   const float* __restrict__ gb,
                   float* __restrict__ out, int T)
{
  // W tile: [k4][expert] float4 -> inner-loop ds_read_b128 is lane-contiguous,
  // 16B-aligned, conflict-free. Double-buffered.
  __shared__ float4 wt[2][NK4][NEXP];

  const int tid  = threadIdx.x;
  const int lane = tid & 63;
  // readfirstlane: make wave id / token base wave-UNIFORM so x loads become s_load
  const int wid  = __builtin_amdgcn_readfirstlane(tid >> 6);
  const int tok0 = __builtin_amdgcn_readfirstlane((int)blockIdx.x * TPBK + wid * TPW);

  float  acc[TPW];   // per-chunk fp32 accumulator (lane = expert)
  double dacc[TPW];  // fp64 chunk combine -> our noise ~3e-7 rms, protects top-k ranking
#pragma unroll
  for (int t = 0; t < TPW; ++t) { acc[t] = 0.f; dacc[t] = 0.0; }

  // prologue: stage chunk 0
#pragma unroll
  for (int j = 0; j < 4; ++j) {
    int s = tid + j * TPB;           // 0..2047 = k4*64 + e
    wt[0][s >> 6][s & 63] = *(const float4*)&Wg[(s & 63) * HIDDEN + 4 * (s >> 6)];
  }
  __syncthreads();

  int cur = 0;
  for (int c = 0; c < NCHUNK; ++c) {
    const int k0 = c * BK;

    // T14 split: issue next-chunk global loads EARLY, ds_write them AFTER compute
    float4 r[4];
    if (c + 1 < NCHUNK) {
#pragma unroll
      for (int j = 0; j < 4; ++j) {
        int s = tid + j * TPB;
        r[j] = *(const float4*)&Wg[(s & 63) * HIDDEN + (k0 + BK) + 4 * (s >> 6)];
      }
    }

#pragma unroll 4
    for (int k4 = 0; k4 < NK4; ++k4) {
      const float4 w = wt[cur][k4][lane];   // lane = expert
#pragma unroll
      for (int t = 0; t < TPW; ++t) {
        // tok0+t, k0, k4 all wave-uniform -> scalar loads (s_load_dwordx4)
        const float4 xv = *(const float4*)&x[(size_t)(tok0 + t) * HIDDEN + (k0 + 4 * k4)];
        acc[t] = fmaf(xv.x, w.x, acc[t]);
        acc[t] = fmaf(xv.y, w.y, acc[t]);
        acc[t] = fmaf(xv.z, w.z, acc[t]);
        acc[t] = fmaf(xv.w, w.w, acc[t]);
      }
    }

    // fold chunk into fp64 master
#pragma unroll
    for (int t = 0; t < TPW; ++t) { dacc[t] += (double)acc[t]; acc[t] = 0.f; }

    if (c + 1 < NCHUNK) {
#pragma unroll
      for (int j = 0; j < 4; ++j) {
        int s = tid + j * TPB;
        wt[cur ^ 1][s >> 6][s & 63] = r[j];
      }
    }
    __syncthreads();
    cur ^= 1;
  }

  // epilogue: bias, top-2 across lanes (lane = expert), softmax over 2
  const float bv = gb[lane];
#pragma unroll
  for (int t = 0; t < TPW; ++t) {
    const float v = (float)dacc[t] + bv;

    float v1 = v; int i1 = lane;
#pragma unroll
    for (int off = 32; off >= 1; off >>= 1) {
      const float ov = __shfl_xor(v1, off, 64);
      const int   oi = __shfl_xor(i1, off, 64);
      if (ov > v1 || (ov == v1 && oi < i1)) { v1 = ov; i1 = oi; }
    }
    float v2 = (lane == i1) ? -3.402823466e+38f : v;
    int   i2 = lane;
#pragma unroll
    for (int off = 32; off >= 1; off >>= 1) {
      const float ov = __shfl_xor(v2, off, 64);
      const int   oi = __shfl_xor(i2, off, 64);
      if (ov > v2 || (ov == v2 && oi < i2)) { v2 = ov; i2 = oi; }
    }

    if (lane == 0) {
      const int tok = tok0 + t;
      const float e2 = expf(v2 - v1);
      const float s  = 1.f + e2;
      out[2 * tok]     = 1.f / s;          // weights (descending, like top_k)
      out[2 * tok + 1] = e2 / s;
      out[2 * T + 2 * tok]     = (float)i1; // idx section (written as float)
      out[2 * T + 2 * tok + 1] = (float)i2;
    }
  }
}

extern "C" void kernel_launch(void* const* d_in, const int* in_sizes, int n_in,
                              void* d_out, int out_size, void* d_ws, size_t ws_size,
                              hipStream_t stream) {
  const float* x  = (const float*)d_in[0];   // [4,8192,2048] f32
  const float* Wg = (const float*)d_in[1];   // [64,2048] f32
  const float* gb = (const float*)d_in[2];   // [64] f32
  float* out = (float*)d_out;                // [2*T weights][2*T idx]
  const int T = in_sizes[0] / HIDDEN;        // 32768 tokens
  router_kernel<<<dim3(T / TPBK), dim3(TPB), 0, stream>>>(x, Wg, gb, out, T);
}

// Round 2
// 177.270 us; speedup vs baseline: 1.8251x; 1.8251x over previous
//
#include <hip/hip_runtime.h>
#include <math.h>

#define HIDDEN 2048
#define NEXP   64
#define BK     64           // k-chunk staged in LDS
#define NK4    (BK/4)       // 16 float4 steps per chunk
#define NCHUNK (HIDDEN/BK)  // 32
#define TPB    512          // 8 waves
#define NWAVE  8
#define TPW    8            // tokens per wave
#define TPBK   64           // tokens per block

typedef __attribute__((address_space(3))) unsigned int       lds_u32;
typedef __attribute__((address_space(1))) const unsigned int gbl_u32;

__global__ __launch_bounds__(TPB, 4)   // 4 waves/EU = 16 waves/CU = 2 blocks/CU
void router_kernel(const float* __restrict__ x,
                   const float* __restrict__ Wg,
                   const float* __restrict__ gb,
                   float* __restrict__ out, int T)
{
  // W chunk [k4][expert] float4: inner ds_read_b128 lane-contiguous, conflict-free.
  // x tile  [wave][tok][k4] float4: consumed as uniform-address broadcasts (free).
  // Both double-buffered; staged ONLY via global_load_lds (zero VGPR, no spill).
  __shared__ float4 wlds[2][NK4][NEXP];        // 32 KB
  __shared__ float4 xlds[2][NWAVE][TPW][NK4];  // 32 KB

  const int tid  = threadIdx.x;
  const int lane = tid & 63;
  const int wid  = tid >> 6;
  const int tok0 = (int)blockIdx.x * TPBK + wid * TPW;

  float  acc[TPW];   // per-chunk fp32 accumulator (lane = expert)
  double dacc[TPW];  // fp64 chunk fold: ~3e-7 total error, protects top-2 ranking
#pragma unroll
  for (int t = 0; t < TPW; ++t) { acc[t] = 0.f; dacc[t] = 0.0; }

  // ---- async staging helpers (LDS dest is lane-linear: base + lane*16) ----
  auto stageW = [&](int buf, int k0) {
#pragma unroll
    for (int j = 0; j < 2; ++j) {
      const int s  = tid + j * TPB;          // 0..1023: k4 = s>>6, e = s&63
      const int e  = s & 63, k4 = s >> 6;
      __builtin_amdgcn_global_load_lds(
          (gbl_u32*)&Wg[(size_t)e * HIDDEN + k0 + 4 * k4],
          (lds_u32*)&wlds[buf][k4][e], 16, 0, 0);
    }
  };
  auto stageX = [&](int buf, int k0) {       // per-wave: 8 tok x 64 floats, coalesced
#pragma unroll
    for (int j = 0; j < 2; ++j) {
      const int s = lane + j * 64;           // 0..127: tok = s>>4, k4 = s&15
      const int t = s >> 4, k4 = s & 15;
      __builtin_amdgcn_global_load_lds(
          (gbl_u32*)&x[(size_t)(tok0 + t) * HIDDEN + k0 + 4 * k4],
          (lds_u32*)&xlds[buf][wid][t][k4], 16, 0, 0);
    }
  };

  stageW(0, 0);
  stageX(0, 0);
  __syncthreads();   // compiler drains vmcnt(0) before s_barrier -> buf 0 ready

  int cur = 0;
  for (int c = 0; c < NCHUNK; ++c) {
    // prefetch next chunk into the other buffer (its last readers passed the
    // previous barrier; loads land under this chunk's ~1000-cycle compute)
    if (c + 1 < NCHUNK) {
      stageW(cur ^ 1, (c + 1) * BK);
      stageX(cur ^ 1, (c + 1) * BK);
    }

#pragma unroll
    for (int k4 = 0; k4 < NK4; ++k4) {
      const float4 w = wlds[cur][k4][lane];          // per-lane b128, conflict-free
#pragma unroll
      for (int t = 0; t < TPW; ++t) {
        const float4 xv = xlds[cur][wid][t][k4];     // uniform b128 broadcast
        acc[t] = fmaf(xv.x, w.x, acc[t]);
        acc[t] = fmaf(xv.y, w.y, acc[t]);
        acc[t] = fmaf(xv.z, w.z, acc[t]);
        acc[t] = fmaf(xv.w, w.w, acc[t]);
      }
    }

#pragma unroll
    for (int t = 0; t < TPW; ++t) { dacc[t] += (double)acc[t]; acc[t] = 0.f; }

    __syncthreads();   // drains this chunk's staging vmcnt + orders buffer reuse
    cur ^= 1;
  }

  // ---- epilogue: bias, wave top-2 (lane = expert), softmax over 2 ----
  const float bv = gb[lane];
#pragma unroll
  for (int t = 0; t < TPW; ++t) {
    const float v = (float)dacc[t] + bv;

    float v1 = v; int i1 = lane;
#pragma unroll
    for (int off = 32; off >= 1; off >>= 1) {
      const float ov = __shfl_xor(v1, off, 64);
      const int   oi = __shfl_xor(i1, off, 64);
      if (ov > v1 || (ov == v1 && oi < i1)) { v1 = ov; i1 = oi; }
    }
    float v2 = (lane == i1) ? -3.402823466e+38f : v;
    int   i2 = lane;
#pragma unroll
    for (int off = 32; off >= 1; off >>= 1) {
      const float ov = __shfl_xor(v2, off, 64);
      const int   oi = __shfl_xor(i2, off, 64);
      if (ov > v2 || (ov == v2 && oi < i2)) { v2 = ov; i2 = oi; }
    }

    if (lane == 0) {
      const int tok = tok0 + t;
      const float e2 = expf(v2 - v1);
      const float s  = 1.f + e2;
      out[2 * tok]     = 1.f / s;            // weights, descending like top_k
      out[2 * tok + 1] = e2 / s;
      out[2 * T + 2 * tok]     = (float)i1;  // idx section (float-encoded)
      out[2 * T + 2 * tok + 1] = (float)i2;
    }
  }
}

extern "C" void kernel_launch(void* const* d_in, const int* in_sizes, int n_in,
                              void* d_out, int out_size, void* d_ws, size_t ws_size,
                              hipStream_t stream) {
  const float* x  = (const float*)d_in[0];   // [4,8192,2048] f32
  const float* Wg = (const float*)d_in[1];   // [64,2048] f32
  const float* gb = (const float*)d_in[2];   // [64] f32
  float* out = (float*)d_out;                // [2*T weights][2*T idx-as-float]
  const int T = in_sizes[0] / HIDDEN;        // 32768 tokens
  router_kernel<<<dim3(T / TPBK), dim3(TPB), 0, stream>>>(x, Wg, gb, out, T);
}